// Round 20
// baseline (72.444 us; speedup 1.0000x reference)
//
#include <hip/hip_runtime.h>
#include <hip/hip_bf16.h>
#include <stdint.h>

#define NPB 8192
#define CB 2
#define CC 128
#define HH 4
#define KTOK 4096
#define DH 32
#define NTOK (CB*KTOK)
#define K2C 0.25503402f  /* log2(e)/sqrt(32) */

typedef __attribute__((ext_vector_type(8))) short sh8;
typedef __attribute__((ext_vector_type(4))) float fx4;
typedef __attribute__((ext_vector_type(16))) float fx16;
typedef __attribute__((ext_vector_type(2))) uint32_t ux2;
typedef __attribute__((ext_vector_type(4))) uint32_t ux4;

__device__ inline uint16_t f2bf(float f){
  uint32_t x = __float_as_uint(f);
  return (uint16_t)((x + 0x7FFFu + ((x>>16)&1u)) >> 16);
}
__device__ inline uint32_t pk2(float a, float b){
  return (uint32_t)f2bf(a) | ((uint32_t)f2bf(b) << 16);
}
__device__ inline float fast_exp2(float x){
#if __has_builtin(__builtin_amdgcn_exp2f)
  return __builtin_amdgcn_exp2f(x);
#else
  return exp2f(x);
#endif
}
__device__ inline uint32_t cvtpk1(float a, float b){
  uint32_t u;
  asm("v_cvt_pk_bf16_f32 %0, %1, %2" : "=v"(u) : "v"(a), "v"(b));
  return u;
}
__device__ inline fx4 mfma32(sh8 a, sh8 b, fx4 c){
  return __builtin_amdgcn_mfma_f32_16x16x32_bf16(a, b, c, 0, 0, 0);
}
__device__ inline fx16 mfma32x32(sh8 a, sh8 b, fx16 c){
  return __builtin_amdgcn_mfma_f32_32x32x16_bf16(a, b, c, 0, 0, 0);
}
__device__ inline void gload_lds(const uint16_t* g, uint16_t* l){
  __builtin_amdgcn_global_load_lds(
      (const __attribute__((address_space(1))) uint32_t*)g,
      (__attribute__((address_space(3))) uint32_t*)l,
      16, 0, 0);
}

/* -------- K1: per-row sqnorm keys + zero selection flags ---------------- */
__global__ __launch_bounds__(256) void k_norms(const float* __restrict__ feats,
                                               uint32_t* __restrict__ keys,
                                               int* __restrict__ flags){
  if (blockIdx.x < 64) flags[blockIdx.x*256 + threadIdx.x] = 0;  /* 16384 */
  int row  = blockIdx.x*4 + (threadIdx.x>>6);
  int lane = threadIdx.x & 63;
  float2 v = *(const float2*)(feats + row*CC + lane*2);
  float s = v.x*v.x + v.y*v.y;
  for (int m = 1; m < 64; m <<= 1) s += __shfl_xor(s, m);
  if (lane == 0) keys[row] = __float_as_uint(s);  /* >=0 -> monotone as uint */
}

/* --- K2: top-4096 selection (blocks 0-1) + weight conversion (2-65) ----- */
__global__ __launch_bounds__(1024) void k_select(const uint32_t* __restrict__ keys,
                                                 int* __restrict__ sel,
                                                 int* __restrict__ flags,
                                                 const float* __restrict__ wq,
                                                 const float* __restrict__ wo,
                                                 uint16_t* __restrict__ wqb,
                                                 uint16_t* __restrict__ wob){
  int tid = threadIdx.x, batch = blockIdx.x;
  if (batch >= 2){
    int i = (batch - 2)*1024 + tid;   /* 0..65535 */
    if (i < 3*CC*CC) wqb[i] = f2bf(wq[i]);
    else { int j = i - 3*CC*CC; wob[j] = f2bf(wo[j]); }
    return;
  }
  __shared__ uint32_t ka[NPB];
  __shared__ uint32_t hist[16*257];
  __shared__ uint32_t sh_prefix, sh_r;
  __shared__ int wsum[17];
  int wv16 = tid >> 6;
  for (int i = tid; i < NPB; i += 1024) ka[i] = keys[batch*NPB + i];
  if (tid == 0){ sh_prefix = 0u; sh_r = KTOK; }
  __syncthreads();
  for (int pass = 0; pass < 4; ++pass){
    int shift = 24 - 8*pass;
    for (int i = tid; i < 16*257; i += 1024) hist[i] = 0u;
    __syncthreads();
    uint32_t pref = sh_prefix;
    uint32_t r0   = sh_r;
    uint32_t mask = (pass == 0) ? 0u : (0xFFFFFFFFu << (shift + 8));
    uint32_t* myh = &hist[wv16*257];
    for (int e = 0; e < 8; ++e){
      uint32_t k = ka[tid*8 + e];
      if ((k & mask) == pref) atomicAdd(&myh[(k >> shift) & 255], 1u);
    }
    __syncthreads();
    if (tid < 64){
      int lane = tid;
      uint32_t h0v = 0, h1v = 0, h2v = 0, h3v = 0;
      int b0 = lane*4;
#pragma unroll
      for (int w = 0; w < 16; ++w){
        const uint32_t* hw = &hist[w*257 + b0];
        h0v += hw[0]; h1v += hw[1]; h2v += hw[2]; h3v += hw[3];
      }
      uint32_t s3 = h3v, s2 = h2v + s3, s1 = h1v + s2, s0 = h0v + s1;
      uint32_t incl = s0;
      for (int d = 1; d < 64; d <<= 1){
        uint32_t t = __shfl_down(incl, d);
        if (lane + d < 64) incl += t;
      }
      uint32_t exA = incl - s0;
      uint32_t sfx[4] = {s0, s1, s2, s3};
      uint32_t hh[4]  = {h0v, h1v, h2v, h3v};
#pragma unroll
      for (int k = 0; k < 4; ++k){
        uint32_t inc_b = exA + sfx[k];
        uint32_t Sx    = inc_b - hh[k];
        if (Sx < r0 && inc_b >= r0){
          sh_prefix = pref | ((uint32_t)(b0 + k) << shift);
          sh_r = r0 - Sx;
        }
      }
    }
    __syncthreads();
  }
  uint32_t T = sh_prefix; int need = (int)sh_r;
  int lgt = 0, leq = 0;
  for (int e = 0; e < 8; ++e){
    uint32_t k = ka[tid*8 + e];
    lgt += (k > T); leq += (k == T);
  }
  int lane = tid & 63, wv = tid >> 6;
  int egt, tgt, eeq;
  {
    __syncthreads();
    int incl = lgt;
    for (int d = 1; d < 64; d <<= 1){ int t = __shfl_up(incl, d); if (lane >= d) incl += t; }
    if (lane == 63) wsum[wv] = incl;
    __syncthreads();
    if (tid == 0){ int run = 0; for (int w = 0; w < 16; ++w){ int t = wsum[w]; wsum[w] = run; run += t; } wsum[16] = run; }
    __syncthreads();
    egt = wsum[wv] + incl - lgt; tgt = wsum[16];
  }
  {
    __syncthreads();
    int incl = leq;
    for (int d = 1; d < 64; d <<= 1){ int t = __shfl_up(incl, d); if (lane >= d) incl += t; }
    if (lane == 63) wsum[wv] = incl;
    __syncthreads();
    if (tid == 0){ int run = 0; for (int w = 0; w < 16; ++w){ int t = wsum[w]; wsum[w] = run; run += t; } }
    __syncthreads();
    eeq = wsum[wv] + incl - leq;
  }
  int chi = tgt, gpos = egt, epos = eeq;
  for (int e = 0; e < 8; ++e){
    int i = tid*8 + e;
    uint32_t k = ka[i];
    int grow = batch*NPB + i;
    if (k > T){ sel[batch*KTOK + (gpos++)] = grow; flags[grow] = 1; }
    else if (k == T){
      if (epos < need){ sel[batch*KTOK + chi + epos] = grow; flags[grow] = 1; }
      epos++;
    }
  }
}

/* ------ K5: QKV projection GEMM, fused gather (8192x384x128) ------------ */
__global__ __launch_bounds__(256) void k_qkv(const float* __restrict__ feats,
                                             const int* __restrict__ sel,
                                             const uint16_t* __restrict__ wqb,
                                             const float* __restrict__ bias,
                                             uint16_t* __restrict__ Qg,
                                             uint16_t* __restrict__ Kg,
                                             uint16_t* __restrict__ Vt){
  int wave = threadIdx.x >> 6, lane = threadIdx.x & 63;
  int l15 = lane & 15, g = lane >> 4;
  int rt = blockIdx.x;               /* 512 row tiles */
  int arow = rt*16 + l15;
  int grow = sel[arow];
  sh8 aF[4];
#pragma unroll
  for (int kk = 0; kk < 4; ++kk){
    const float* src = feats + grow*CC + kk*32 + g*8;
    float4 v0 = *(const float4*)(src);
    float4 v1 = *(const float4*)(src + 4);
    ux4 u;
    u.x = cvtpk1(v0.x, v0.y);
    u.y = cvtpk1(v0.z, v0.w);
    u.z = cvtpk1(v1.x, v1.y);
    u.w = cvtpk1(v1.z, v1.w);
    aF[kk] = *(sh8*)&u;
  }
  int tbase = rt*16;
  int b  = tbase >> 12;
  int q0 = (tbase & 4095) + g*4;     /* 4 consecutive within-batch slots */
#pragma unroll
  for (int cg = 0; cg < 6; ++cg){
    int bcol = (cg*4 + wave)*16 + l15;
    fx4 acc = {0.f,0.f,0.f,0.f};
#pragma unroll
    for (int kk = 0; kk < 4; ++kk){
      sh8 bF = *(const sh8*)(wqb + bcol*CC + kk*32 + g*8);
      acc = mfma32(aF[kk], bF, acc);
    }
    int j = bcol;
    float bj = bias[j];
    if (j < CC){
      int h = j >> 5, d = j & 31;
      uint16_t* p = Qg + ((b*HH + h)*KTOK + q0)*DH + d;
#pragma unroll
      for (int i = 0; i < 4; ++i) p[i*DH] = f2bf((acc[i] + bj) * K2C);
    } else if (j < 2*CC){
      int jj = j - CC; int h = jj >> 5, d = jj & 31;
      uint16_t* p = Kg + ((b*HH + h)*KTOK + q0)*DH + d;
#pragma unroll
      for (int i = 0; i < 4; ++i) p[i*DH] = f2bf(acc[i] + bj);
    } else {
      int jj = j - 2*CC; int h = jj >> 5, d = jj & 31;
      uint16_t* p = Vt + ((b*HH + h)*DH + d)*KTOK + q0;
      ux2 w; w.x = pk2(acc[0]+bj, acc[1]+bj); w.y = pk2(acc[2]+bj, acc[3]+bj);
      *(ux2*)p = w;
    }
  }
}

/* ---- K6: attention — R19-proven (128q, K-perm kappa, MFMA l-sum) ------- */
__global__ __launch_bounds__(1024) void k_attn(const uint16_t* __restrict__ Qg,
                                               const uint16_t* __restrict__ Kg,
                                               const uint16_t* __restrict__ Vtg,
                                               uint16_t* __restrict__ O){
  __shared__ __align__(16) char lds[68096];
  int tid = threadIdx.x;
  int wv = tid >> 6, lane = tid & 63;
  int l31 = lane & 31, hi = lane >> 5;
  int seg = wv & 3, tq = wv >> 2;      /* seg 0..3, tq 0..3 */
  int bh = blockIdx.y;
  int qt = blockIdx.x;                 /* 32 q128-tiles per bh */
  const uint16_t* Qp = Qg  + bh*KTOK*DH;
  const uint16_t* Kp = Kg  + bh*KTOK*DH;
  const uint16_t* Vp = Vtg + bh*DH*KTOK;
  int q = qt*128 + tq*32 + l31;
  sh8 qF0 = *(const sh8*)(Qp + q*DH + hi*8);        /* B: col=q, k=dh 0..15  */
  sh8 qF1 = *(const sh8*)(Qp + q*DH + 16 + hi*8);   /* B: col=q, k=dh 16..31 */

  uint16_t* st = (uint16_t*)lds;   /* [2 buf][4 seg][K0|K1|V0|V1] 1024-elem blocks */
  int r16 = lane >> 2;
  int kr  = (r16 & 3) | ((r16 & 4) << 1) | ((r16 & 8) >> 1);  /* kappa source row */
  int sx  = ((lane & 3) ^ ((r16 >> 1) & 3)) * 8;   /* dest-row-keyed swizzled slot */
  int sseg = wv & 3;
  int skey0 = sseg*1024;

  /* prologue: chunk 0 -> buf0 (waves 0-3: K permuted, 4-7: V natural) */
  if (wv < 4){
    const uint16_t* kg = Kp + skey0*DH;
    uint16_t* d = st + sseg*4096;
#pragma unroll
    for (int ks = 0; ks < 2; ++ks){
      gload_lds(kg + (ks*32 + kr)*DH + sx,      d + ks*1024 + 0);
      gload_lds(kg + (ks*32 + 16 + kr)*DH + sx, d + ks*1024 + 512);
    }
  } else if (wv < 8){
    const uint16_t* vg = Vp + skey0;
    uint16_t* d = st + sseg*4096 + 2048;
#pragma unroll
    for (int ks = 0; ks < 2; ++ks){
      gload_lds(vg + r16*KTOK + ks*32 + sx,        d + ks*1024 + 0);
      gload_lds(vg + (16+r16)*KTOK + ks*32 + sx,   d + ks*1024 + 512);
    }
  }
  asm volatile("s_waitcnt vmcnt(0)" ::: "memory");
  __syncthreads();

  fx16 acc  = {0,0,0,0,0,0,0,0,0,0,0,0,0,0,0,0};
  fx16 accl = {0,0,0,0,0,0,0,0,0,0,0,0,0,0,0,0};
  const fx16 z16 = {0,0,0,0,0,0,0,0,0,0,0,0,0,0,0,0};
  const short ONEB = (short)0x3F80;
  sh8 onesB = {ONEB,ONEB,ONEB,ONEB,ONEB,ONEB,ONEB,ONEB};
  int swz = (l31 >> 1) & 3;
  int koff0 = l31*32 + ((hi     ^ swz)*8);
  int koff1 = l31*32 + (((hi+2) ^ swz)*8);

  for (int t = 0; t < 16; ++t){
    int b = t & 1;
    if (t < 15){
      int nk = skey0 + (t+1)*64;
      if (wv < 4){
        const uint16_t* kg = Kp + nk*DH;
        uint16_t* d = st + ((b^1)*4 + sseg)*4096;
#pragma unroll
        for (int ks = 0; ks < 2; ++ks){
          gload_lds(kg + (ks*32 + kr)*DH + sx,      d + ks*1024 + 0);
          gload_lds(kg + (ks*32 + 16 + kr)*DH + sx, d + ks*1024 + 512);
        }
      } else if (wv < 8){
        const uint16_t* vg = Vp + nk;
        uint16_t* d = st + ((b^1)*4 + sseg)*4096 + 2048;
#pragma unroll
        for (int ks = 0; ks < 2; ++ks){
          gload_lds(vg + r16*KTOK + ks*32 + sx,        d + ks*1024 + 0);
          gload_lds(vg + (16+r16)*KTOK + ks*32 + sx,   d + ks*1024 + 512);
        }
      }
    }
    const uint16_t* base = st + (b*4 + seg)*4096;
#pragma unroll
    for (int ks = 0; ks < 2; ++ks){
      const uint16_t* bK = base + ks*1024;
      const uint16_t* bV = base + 2048 + ks*1024;
      sh8 kA0 = *(const sh8*)(bK + koff0);
      sh8 kA1 = *(const sh8*)(bK + koff1);
      fx16 S = mfma32x32(kA0, qF0, z16);
      S = mfma32x32(kA1, qF1, S);
      float e[16];
#pragma unroll
      for (int r = 0; r < 16; ++r) e[r] = fast_exp2(S[r]);
      ux4 w0, w1;
      w0.x = cvtpk1(e[0],  e[1]);  w0.y = cvtpk1(e[2],  e[3]);
      w0.z = cvtpk1(e[4],  e[5]);  w0.w = cvtpk1(e[6],  e[7]);
      w1.x = cvtpk1(e[8],  e[9]);  w1.y = cvtpk1(e[10], e[11]);
      w1.z = cvtpk1(e[12], e[13]); w1.w = cvtpk1(e[14], e[15]);
      sh8 pa0 = *(sh8*)&w0;   /* A: row=q, k=keys 0..15 (kappa-matched) */
      sh8 pa1 = *(sh8*)&w1;   /* A: row=q, k=keys 16..31                */
      sh8 vB0 = *(const sh8*)(bV + koff0);
      sh8 vB1 = *(const sh8*)(bV + koff1);
      acc  = mfma32x32(pa0, vB0, acc);
      acc  = mfma32x32(pa1, vB1, acc);
      accl = mfma32x32(pa0, onesB, accl);
      accl = mfma32x32(pa1, onesB, accl);
    }
    asm volatile("s_waitcnt vmcnt(0)" ::: "memory");
    __syncthreads();
  }

  /* combine 4 segments x 4 tiles; staging LDS reused after final barrier */
  float* cmb = (float*)lds;                    /* [4 tq][4 seg][64][16] = 64KB */
  float* lwp = (float*)(lds + 65536);          /* [16][32] = 2KB               */
  float* ltr = (float*)(lds + 65536 + 2048);   /* [4][32]                      */
#pragma unroll
  for (int i = 0; i < 16; i += 4){
    fx4 p = {acc[i], acc[i+1], acc[i+2], acc[i+3]};
    *(fx4*)&cmb[((tq*4 + seg)*64 + lane)*16 + i] = p;
  }
  if (l31 == 0){   /* lanes 0,32: accl[r] = l(q=crow(r,hi)), same every col */
#pragma unroll
    for (int r = 0; r < 16; ++r)
      lwp[wv*32 + (r&3) + 8*(r>>2) + 4*hi] = accl[r];
  }
  __syncthreads();
  if (seg == 0){   /* waves 0,4,8,12 -> tiles tq=0..3 */
#pragma unroll
    for (int s = 1; s < 4; ++s){
#pragma unroll
      for (int i = 0; i < 16; i += 4){
        fx4 p = *(const fx4*)&cmb[((tq*4 + s)*64 + lane)*16 + i];
        acc[i] += p.x; acc[i+1] += p.y; acc[i+2] += p.z; acc[i+3] += p.w;
      }
    }
    float lt = (lwp[(tq*4+0)*32 + l31] + lwp[(tq*4+1)*32 + l31])
             + (lwp[(tq*4+2)*32 + l31] + lwp[(tq*4+3)*32 + l31]);
    if (!hi) ltr[tq*32 + l31] = lt;
    fx4 La = *(const fx4*)&ltr[tq*32 + 4*hi];
    fx4 Lb = *(const fx4*)&ltr[tq*32 + 8 + 4*hi];
    fx4 Lc = *(const fx4*)&ltr[tq*32 + 16 + 4*hi];
    fx4 Ld = *(const fx4*)&ltr[tq*32 + 24 + 4*hi];
    fx4 Ra = {1.f/La.x, 1.f/La.y, 1.f/La.z, 1.f/La.w};
    fx4 Rb = {1.f/Lb.x, 1.f/Lb.y, 1.f/Lb.z, 1.f/Lb.w};
    fx4 Rc = {1.f/Lc.x, 1.f/Lc.y, 1.f/Lc.z, 1.f/Lc.w};
    fx4 Rd = {1.f/Ld.x, 1.f/Ld.y, 1.f/Ld.z, 1.f/Ld.w};
    int bb = bh >> 2, h = bh & 3;
    uint16_t* op = O + (bb*KTOK + qt*128 + tq*32)*CC + h*DH + l31;
#pragma unroll
    for (int r = 0; r < 16; ++r){
      int qd = (r&3) + 8*(r>>2) + 4*hi;
      float rv = (r<4) ? Ra[r&3] : (r<8) ? Rb[r&3] : (r<12) ? Rc[r&3] : Rd[r&3];
      op[qd*CC] = f2bf(acc[r] * rv);
    }
  }
}

/* -- K7: out-proj + residual + LN + scatter (blocks 0-511) ----------------
      + flag-gated copy of non-selected rows (blocks 512-1023) ------------ */
__global__ __launch_bounds__(256) void k_outln(const uint16_t* __restrict__ O,
                                               const uint16_t* __restrict__ wob,
                                               const float* __restrict__ bo,
                                               const float* __restrict__ feats,
                                               const int* __restrict__ sel,
                                               const int* __restrict__ flags,
                                               const float* __restrict__ lnw,
                                               const float* __restrict__ lnb,
                                               float* __restrict__ out){
  int bx = blockIdx.x;
  if (bx >= 512){
    /* copy blocks: 32 rows each, skip selected rows */
    int cb = bx - 512;
    int row = cb*32 + (threadIdx.x >> 3);
    int c0  = (threadIdx.x & 7) * 16;
    if (!flags[row]){
      const float4* s = (const float4*)(feats + row*CC + c0);
      float4* d = (float4*)(out + row*CC + c0);
      d[0] = s[0]; d[1] = s[1]; d[2] = s[2]; d[3] = s[3];
    }
    return;
  }
  __shared__ float red[16][4][2];
  int wave = threadIdx.x >> 6, lane = threadIdx.x & 63;
  int l15 = lane & 15, g = lane >> 4;
  int rt = bx;
  int arow = rt*16 + l15;
  int jA = wave*32 + l15, jB = jA + 16;
  fx4 accA = {0,0,0,0}, accB = {0,0,0,0};
#pragma unroll
  for (int kk = 0; kk < 4; ++kk){
    sh8 aF = *(const sh8*)(O   + arow*CC + kk*32 + g*8);
    sh8 b0 = *(const sh8*)(wob + jA*CC   + kk*32 + g*8);
    sh8 b1 = *(const sh8*)(wob + jB*CC   + kk*32 + g*8);
    accA = mfma32(aF, b0, accA);
    accB = mfma32(aF, b1, accB);
  }
  float bjA = bo[jA], bjB = bo[jB];
  float hA[4], hB[4]; int gl[4];
#pragma unroll
  for (int i = 0; i < 4; ++i){
    int r = rt*16 + g*4 + i;
    int grow = sel[r];
    gl[i] = grow;
    hA[i] = accA[i] + bjA + feats[grow*CC + jA];
    hB[i] = accB[i] + bjB + feats[grow*CC + jB];
  }
#pragma unroll
  for (int i = 0; i < 4; ++i){
    float s  = hA[i] + hB[i];
    float s2 = hA[i]*hA[i] + hB[i]*hB[i];
    for (int mk = 1; mk < 16; mk <<= 1){ s += __shfl_xor(s, mk); s2 += __shfl_xor(s2, mk); }
    if (l15 == 0){ red[g*4+i][wave][0] = s; red[g*4+i][wave][1] = s2; }
  }
  __syncthreads();
  float w0 = lnw[jA], w1 = lnw[jB], b0v = lnb[jA], b1v = lnb[jB];
#pragma unroll
  for (int i = 0; i < 4; ++i){
    int rl = g*4 + i;
    float tot  = red[rl][0][0] + red[rl][1][0] + red[rl][2][0] + red[rl][3][0];
    float tot2 = red[rl][0][1] + red[rl][1][1] + red[rl][2][1] + red[rl][3][1];
    float mu  = tot  * (1.f/128.f);
    float var = tot2 * (1.f/128.f) - mu*mu;
    float rs = rsqrtf(var + 1e-5f);
    out[gl[i]*CC + jA] = (hA[i]-mu)*rs*w0 + b0v;
    out[gl[i]*CC + jB] = (hB[i]-mu)*rs*w1 + b1v;
  }
}

extern "C" void kernel_launch(void* const* d_in, const int* in_sizes, int n_in,
                              void* d_out, int out_size, void* d_ws, size_t ws_size,
                              hipStream_t stream){
  const float* feats = (const float*)d_in[0];
  /* d_in[1] = batch_idx (int64) — contiguous equal groups, unused */
  const float* wqkv  = (const float*)d_in[2];
  const float* bqkv  = (const float*)d_in[3];
  const float* wout  = (const float*)d_in[4];
  const float* bout  = (const float*)d_in[5];
  const float* lnw   = (const float*)d_in[6];
  const float* lnb   = (const float*)d_in[7];
  float* out = (float*)d_out;
  char* ws = (char*)d_ws;

  uint32_t* keys = (uint32_t*)(ws + 0);        /* 64KB  */
  int*      sel  = (int*)     (ws + 65536);    /* 32KB  */
  uint16_t* wqb  = (uint16_t*)(ws + 98304);    /* 96KB  */
  uint16_t* wob  = (uint16_t*)(ws + 196608);   /* 32KB  */
  int*      flags= (int*)     (ws + 229376);   /* 64KB  */
  uint16_t* Qg   = (uint16_t*)(ws + 2326528);  /* 2MB   */
  uint16_t* Kg   = (uint16_t*)(ws + 4423680);  /* 2MB   */
  uint16_t* Vt   = (uint16_t*)(ws + 6520832);  /* 2MB   */
  uint16_t* O    = (uint16_t*)(ws + 8617984);  /* 2MB   */

  hipLaunchKernelGGL(k_norms,  dim3(4096),   dim3(256),  0, stream, feats, keys, flags);
  hipLaunchKernelGGL(k_select, dim3(66),     dim3(1024), 0, stream,
                     keys, sel, flags, wqkv, wout, wqb, wob);
  hipLaunchKernelGGL(k_qkv,    dim3(512),    dim3(256),  0, stream,
                     feats, sel, wqb, bqkv, Qg, Kg, Vt);
  hipLaunchKernelGGL(k_attn,   dim3(32,8),   dim3(1024), 0, stream, Qg, Kg, Vt, O);
  hipLaunchKernelGGL(k_outln,  dim3(1024),   dim3(256),  0, stream,
                     O, wob, bout, feats, sel, flags, lnw, lnb, out);
}

// Round 21
// 71.121 us; speedup vs baseline: 1.0186x; 1.0186x over previous
//
#include <hip/hip_runtime.h>
#include <hip/hip_bf16.h>
#include <stdint.h>

#define NPB 8192
#define CB 2
#define CC 128
#define HH 4
#define KTOK 4096
#define DH 32
#define NTOK (CB*KTOK)
#define K2C 0.25503402f  /* log2(e)/sqrt(32) */

typedef __attribute__((ext_vector_type(8))) short sh8;
typedef __attribute__((ext_vector_type(4))) float fx4;
typedef __attribute__((ext_vector_type(16))) float fx16;
typedef __attribute__((ext_vector_type(2))) uint32_t ux2;
typedef __attribute__((ext_vector_type(4))) uint32_t ux4;

__device__ inline uint16_t f2bf(float f){
  uint32_t x = __float_as_uint(f);
  return (uint16_t)((x + 0x7FFFu + ((x>>16)&1u)) >> 16);
}
__device__ inline uint32_t pk2(float a, float b){
  return (uint32_t)f2bf(a) | ((uint32_t)f2bf(b) << 16);
}
__device__ inline float fast_exp2(float x){
#if __has_builtin(__builtin_amdgcn_exp2f)
  return __builtin_amdgcn_exp2f(x);
#else
  return exp2f(x);
#endif
}
__device__ inline uint32_t cvtpk1(float a, float b){
  uint32_t u;
  asm("v_cvt_pk_bf16_f32 %0, %1, %2" : "=v"(u) : "v"(a), "v"(b));
  return u;
}
__device__ inline fx4 mfma32(sh8 a, sh8 b, fx4 c){
  return __builtin_amdgcn_mfma_f32_16x16x32_bf16(a, b, c, 0, 0, 0);
}
__device__ inline fx16 mfma32x32(sh8 a, sh8 b, fx16 c){
  return __builtin_amdgcn_mfma_f32_32x32x16_bf16(a, b, c, 0, 0, 0);
}
__device__ inline void gload_lds(const uint16_t* g, uint16_t* l){
  __builtin_amdgcn_global_load_lds(
      (const __attribute__((address_space(1))) uint32_t*)g,
      (__attribute__((address_space(3))) uint32_t*)l,
      16, 0, 0);
}

/* -------- K0: copy feats -> out + sqnorm keys + weight conversion ------- */
__global__ __launch_bounds__(256) void k_cpnw(const float* __restrict__ feats,
                                              float* __restrict__ out,
                                              uint32_t* __restrict__ keys,
                                              const float* __restrict__ wq,
                                              const float* __restrict__ wo,
                                              uint16_t* __restrict__ wqb,
                                              uint16_t* __restrict__ wob){
  int bx = blockIdx.x;
  if (bx < 1024){
    int wv = threadIdx.x >> 6, lane = threadIdx.x & 63;
    int row0 = bx*16 + wv*4;
#pragma unroll
    for (int r = 0; r < 4; ++r){
      int row = row0 + r;
      float2 v = *(const float2*)(feats + row*CC + lane*2);
      *(float2*)(out + row*CC + lane*2) = v;
      float s = v.x*v.x + v.y*v.y;
      for (int m = 1; m < 64; m <<= 1) s += __shfl_xor(s, m);
      if (lane == 0) keys[row] = __float_as_uint(s);
    }
  } else {
    int i = (bx - 1024)*256 + threadIdx.x;   /* 0..65535 */
    if (i < 3*CC*CC) wqb[i] = f2bf(wq[i]);
    else { int j = i - 3*CC*CC; wob[j] = f2bf(wo[j]); }
  }
}

/* ---------------- K2: exact top-4096 selection per batch ---------------- */
__global__ __launch_bounds__(1024) void k_select(const uint32_t* __restrict__ keys,
                                                 int* __restrict__ sel){
  __shared__ uint32_t ka[NPB];
  __shared__ uint32_t hist[16*257];
  __shared__ uint32_t sh_prefix, sh_r;
  __shared__ int wsum[17];
  int tid = threadIdx.x, batch = blockIdx.x;
  int wv16 = tid >> 6;
  for (int i = tid; i < NPB; i += 1024) ka[i] = keys[batch*NPB + i];
  if (tid == 0){ sh_prefix = 0u; sh_r = KTOK; }
  __syncthreads();
  for (int pass = 0; pass < 4; ++pass){
    int shift = 24 - 8*pass;
    for (int i = tid; i < 16*257; i += 1024) hist[i] = 0u;
    __syncthreads();
    uint32_t pref = sh_prefix;
    uint32_t r0   = sh_r;
    uint32_t mask = (pass == 0) ? 0u : (0xFFFFFFFFu << (shift + 8));
    uint32_t* myh = &hist[wv16*257];
    for (int e = 0; e < 8; ++e){
      uint32_t k = ka[tid*8 + e];
      if ((k & mask) == pref) atomicAdd(&myh[(k >> shift) & 255], 1u);
    }
    __syncthreads();
    if (tid < 64){
      int lane = tid;
      uint32_t h0v = 0, h1v = 0, h2v = 0, h3v = 0;
      int b0 = lane*4;
#pragma unroll
      for (int w = 0; w < 16; ++w){
        const uint32_t* hw = &hist[w*257 + b0];
        h0v += hw[0]; h1v += hw[1]; h2v += hw[2]; h3v += hw[3];
      }
      uint32_t s3 = h3v, s2 = h2v + s3, s1 = h1v + s2, s0 = h0v + s1;
      uint32_t incl = s0;
      for (int d = 1; d < 64; d <<= 1){
        uint32_t t = __shfl_down(incl, d);
        if (lane + d < 64) incl += t;
      }
      uint32_t exA = incl - s0;
      uint32_t sfx[4] = {s0, s1, s2, s3};
      uint32_t hh[4]  = {h0v, h1v, h2v, h3v};
#pragma unroll
      for (int k = 0; k < 4; ++k){
        uint32_t inc_b = exA + sfx[k];
        uint32_t Sx    = inc_b - hh[k];
        if (Sx < r0 && inc_b >= r0){
          sh_prefix = pref | ((uint32_t)(b0 + k) << shift);
          sh_r = r0 - Sx;
        }
      }
    }
    __syncthreads();
  }
  uint32_t T = sh_prefix; int need = (int)sh_r;
  int lgt = 0, leq = 0;
  for (int e = 0; e < 8; ++e){
    uint32_t k = ka[tid*8 + e];
    lgt += (k > T); leq += (k == T);
  }
  int lane = tid & 63, wv = tid >> 6;
  int egt, tgt, eeq;
  {
    __syncthreads();
    int incl = lgt;
    for (int d = 1; d < 64; d <<= 1){ int t = __shfl_up(incl, d); if (lane >= d) incl += t; }
    if (lane == 63) wsum[wv] = incl;
    __syncthreads();
    if (tid == 0){ int run = 0; for (int w = 0; w < 16; ++w){ int t = wsum[w]; wsum[w] = run; run += t; } wsum[16] = run; }
    __syncthreads();
    egt = wsum[wv] + incl - lgt; tgt = wsum[16];
  }
  {
    __syncthreads();
    int incl = leq;
    for (int d = 1; d < 64; d <<= 1){ int t = __shfl_up(incl, d); if (lane >= d) incl += t; }
    if (lane == 63) wsum[wv] = incl;
    __syncthreads();
    if (tid == 0){ int run = 0; for (int w = 0; w < 16; ++w){ int t = wsum[w]; wsum[w] = run; run += t; } }
    __syncthreads();
    eeq = wsum[wv] + incl - leq;
  }
  int chi = tgt, gpos = egt, epos = eeq;
  for (int e = 0; e < 8; ++e){
    int i = tid*8 + e;
    uint32_t k = ka[i];
    if (k > T){ sel[batch*KTOK + (gpos++)] = batch*NPB + i; }
    else if (k == T){ if (epos < need) sel[batch*KTOK + chi + epos] = batch*NPB + i; epos++; }
  }
}

/* ------ K5: QKV projection GEMM, fused gather (8192x384x128) ------------ */
__global__ __launch_bounds__(256) void k_qkv(const float* __restrict__ feats,
                                             const int* __restrict__ sel,
                                             const uint16_t* __restrict__ wqb,
                                             const float* __restrict__ bias,
                                             uint16_t* __restrict__ Qg,
                                             uint16_t* __restrict__ Kg,
                                             uint16_t* __restrict__ Vt){
  int wave = threadIdx.x >> 6, lane = threadIdx.x & 63;
  int l15 = lane & 15, g = lane >> 4;
  int rt = blockIdx.x;               /* 512 row tiles */
  int arow = rt*16 + l15;
  int grow = sel[arow];
  sh8 aF[4];
#pragma unroll
  for (int kk = 0; kk < 4; ++kk){
    const float* src = feats + grow*CC + kk*32 + g*8;
    float4 v0 = *(const float4*)(src);
    float4 v1 = *(const float4*)(src + 4);
    ux4 u;
    u.x = cvtpk1(v0.x, v0.y);
    u.y = cvtpk1(v0.z, v0.w);
    u.z = cvtpk1(v1.x, v1.y);
    u.w = cvtpk1(v1.z, v1.w);
    aF[kk] = *(sh8*)&u;
  }
  int tbase = rt*16;
  int b  = tbase >> 12;
  int q0 = (tbase & 4095) + g*4;     /* 4 consecutive within-batch slots */
#pragma unroll
  for (int cg = 0; cg < 6; ++cg){
    int bcol = (cg*4 + wave)*16 + l15;
    fx4 acc = {0.f,0.f,0.f,0.f};
#pragma unroll
    for (int kk = 0; kk < 4; ++kk){
      sh8 bF = *(const sh8*)(wqb + bcol*CC + kk*32 + g*8);
      acc = mfma32(aF[kk], bF, acc);
    }
    int j = bcol;
    float bj = bias[j];
    if (j < CC){
      int h = j >> 5, d = j & 31;
      uint16_t* p = Qg + ((b*HH + h)*KTOK + q0)*DH + d;
#pragma unroll
      for (int i = 0; i < 4; ++i) p[i*DH] = f2bf((acc[i] + bj) * K2C);
    } else if (j < 2*CC){
      int jj = j - CC; int h = jj >> 5, d = jj & 31;
      uint16_t* p = Kg + ((b*HH + h)*KTOK + q0)*DH + d;
#pragma unroll
      for (int i = 0; i < 4; ++i) p[i*DH] = f2bf(acc[i] + bj);
    } else {
      int jj = j - 2*CC; int h = jj >> 5, d = jj & 31;
      uint16_t* p = Vt + ((b*HH + h)*DH + d)*KTOK + q0;
      ux2 w; w.x = pk2(acc[0]+bj, acc[1]+bj); w.y = pk2(acc[2]+bj, acc[3]+bj);
      *(ux2*)p = w;
    }
  }
}

/* ---- K6: attention — 128q blocks, R17 sync, K-perm + MFMA l-sum -------- */
__global__ __launch_bounds__(1024) void k_attn(const uint16_t* __restrict__ Qg,
                                               const uint16_t* __restrict__ Kg,
                                               const uint16_t* __restrict__ Vtg,
                                               uint16_t* __restrict__ O){
  __shared__ __align__(16) char lds[68096];
  int tid = threadIdx.x;
  int wv = tid >> 6, lane = tid & 63;
  int l31 = lane & 31, hi = lane >> 5;
  int seg = wv & 3, tq = wv >> 2;      /* seg 0..3, tq 0..3 */
  int bh = blockIdx.y;
  int qt = blockIdx.x;                 /* 32 q128-tiles per bh */
  const uint16_t* Qp = Qg  + bh*KTOK*DH;
  const uint16_t* Kp = Kg  + bh*KTOK*DH;
  const uint16_t* Vp = Vtg + bh*DH*KTOK;
  int q = qt*128 + tq*32 + l31;
  sh8 qF0 = *(const sh8*)(Qp + q*DH + hi*8);        /* B: col=q, k=dh 0..15  */
  sh8 qF1 = *(const sh8*)(Qp + q*DH + 16 + hi*8);   /* B: col=q, k=dh 16..31 */

  uint16_t* st = (uint16_t*)lds;   /* [2 buf][4 seg][K0|K1|V0|V1] 1024-elem blocks */
  int r16 = lane >> 2;
  int kr  = (r16 & 3) | ((r16 & 4) << 1) | ((r16 & 8) >> 1);  /* kappa source row */
  int sx  = ((lane & 3) ^ ((r16 >> 1) & 3)) * 8;   /* dest-row-keyed swizzled slot */
  int sseg = wv & 3;
  int skey0 = sseg*1024;

  /* prologue: chunk 0 -> buf0 (waves 0-3: K permuted, 4-7: V natural) */
  if (wv < 4){
    const uint16_t* kg = Kp + skey0*DH;
    uint16_t* d = st + sseg*4096;
#pragma unroll
    for (int ks = 0; ks < 2; ++ks){
      gload_lds(kg + (ks*32 + kr)*DH + sx,      d + ks*1024 + 0);
      gload_lds(kg + (ks*32 + 16 + kr)*DH + sx, d + ks*1024 + 512);
    }
  } else if (wv < 8){
    const uint16_t* vg = Vp + skey0;
    uint16_t* d = st + sseg*4096 + 2048;
#pragma unroll
    for (int ks = 0; ks < 2; ++ks){
      gload_lds(vg + r16*KTOK + ks*32 + sx,        d + ks*1024 + 0);
      gload_lds(vg + (16+r16)*KTOK + ks*32 + sx,   d + ks*1024 + 512);
    }
  }
  asm volatile("s_waitcnt vmcnt(0)" ::: "memory");
  __syncthreads();

  fx16 acc  = {0,0,0,0,0,0,0,0,0,0,0,0,0,0,0,0};
  fx16 accl = {0,0,0,0,0,0,0,0,0,0,0,0,0,0,0,0};
  const fx16 z16 = {0,0,0,0,0,0,0,0,0,0,0,0,0,0,0,0};
  const short ONEB = (short)0x3F80;
  sh8 onesB = {ONEB,ONEB,ONEB,ONEB,ONEB,ONEB,ONEB,ONEB};
  int swz = (l31 >> 1) & 3;
  int koff0 = l31*32 + ((hi     ^ swz)*8);
  int koff1 = l31*32 + (((hi+2) ^ swz)*8);

  for (int t = 0; t < 16; ++t){
    int b = t & 1;
    if (t < 15){
      int nk = skey0 + (t+1)*64;
      if (wv < 4){
        const uint16_t* kg = Kp + nk*DH;
        uint16_t* d = st + ((b^1)*4 + sseg)*4096;
#pragma unroll
        for (int ks = 0; ks < 2; ++ks){
          gload_lds(kg + (ks*32 + kr)*DH + sx,      d + ks*1024 + 0);
          gload_lds(kg + (ks*32 + 16 + kr)*DH + sx, d + ks*1024 + 512);
        }
      } else if (wv < 8){
        const uint16_t* vg = Vp + nk;
        uint16_t* d = st + ((b^1)*4 + sseg)*4096 + 2048;
#pragma unroll
        for (int ks = 0; ks < 2; ++ks){
          gload_lds(vg + r16*KTOK + ks*32 + sx,        d + ks*1024 + 0);
          gload_lds(vg + (16+r16)*KTOK + ks*32 + sx,   d + ks*1024 + 512);
        }
      }
    }
    const uint16_t* base = st + (b*4 + seg)*4096;
#pragma unroll
    for (int ks = 0; ks < 2; ++ks){
      const uint16_t* bK = base + ks*1024;
      const uint16_t* bV = base + 2048 + ks*1024;
      sh8 kA0 = *(const sh8*)(bK + koff0);
      sh8 kA1 = *(const sh8*)(bK + koff1);
      fx16 S = mfma32x32(kA0, qF0, z16);
      S = mfma32x32(kA1, qF1, S);
      float e[16];
#pragma unroll
      for (int r = 0; r < 16; ++r) e[r] = fast_exp2(S[r]);
      ux4 w0, w1;
      w0.x = cvtpk1(e[0],  e[1]);  w0.y = cvtpk1(e[2],  e[3]);
      w0.z = cvtpk1(e[4],  e[5]);  w0.w = cvtpk1(e[6],  e[7]);
      w1.x = cvtpk1(e[8],  e[9]);  w1.y = cvtpk1(e[10], e[11]);
      w1.z = cvtpk1(e[12], e[13]); w1.w = cvtpk1(e[14], e[15]);
      sh8 pa0 = *(sh8*)&w0;   /* A: row=q, k=keys 0..15 (kappa-matched) */
      sh8 pa1 = *(sh8*)&w1;   /* A: row=q, k=keys 16..31                */
      sh8 vB0 = *(const sh8*)(bV + koff0);
      sh8 vB1 = *(const sh8*)(bV + koff1);
      acc  = mfma32x32(pa0, vB0, acc);
      acc  = mfma32x32(pa1, vB1, acc);
      accl = mfma32x32(pa0, onesB, accl);
      accl = mfma32x32(pa1, onesB, accl);
    }
    asm volatile("s_waitcnt vmcnt(0)" ::: "memory");
    __syncthreads();
  }

  /* combine 4 segments x 4 tiles; staging LDS reused after final barrier */
  float* cmb = (float*)lds;                    /* [4 tq][4 seg][64][16] = 64KB */
  float* lwp = (float*)(lds + 65536);          /* [16][32] = 2KB               */
  float* ltr = (float*)(lds + 65536 + 2048);   /* [4][32]                      */
#pragma unroll
  for (int i = 0; i < 16; i += 4){
    fx4 p = {acc[i], acc[i+1], acc[i+2], acc[i+3]};
    *(fx4*)&cmb[((tq*4 + seg)*64 + lane)*16 + i] = p;
  }
  if (l31 == 0){   /* lanes 0,32: accl[r] = l(q=crow(r,hi)), same every col */
#pragma unroll
    for (int r = 0; r < 16; ++r)
      lwp[wv*32 + (r&3) + 8*(r>>2) + 4*hi] = accl[r];
  }
  __syncthreads();
  if (seg == 0){   /* waves 0,4,8,12 -> tiles tq=0..3 */
#pragma unroll
    for (int s = 1; s < 4; ++s){
#pragma unroll
      for (int i = 0; i < 16; i += 4){
        fx4 p = *(const fx4*)&cmb[((tq*4 + s)*64 + lane)*16 + i];
        acc[i] += p.x; acc[i+1] += p.y; acc[i+2] += p.z; acc[i+3] += p.w;
      }
    }
    float lt = (lwp[(tq*4+0)*32 + l31] + lwp[(tq*4+1)*32 + l31])
             + (lwp[(tq*4+2)*32 + l31] + lwp[(tq*4+3)*32 + l31]);
    if (!hi) ltr[tq*32 + l31] = lt;
    fx4 La = *(const fx4*)&ltr[tq*32 + 4*hi];
    fx4 Lb = *(const fx4*)&ltr[tq*32 + 8 + 4*hi];
    fx4 Lc = *(const fx4*)&ltr[tq*32 + 16 + 4*hi];
    fx4 Ld = *(const fx4*)&ltr[tq*32 + 24 + 4*hi];
    fx4 Ra = {1.f/La.x, 1.f/La.y, 1.f/La.z, 1.f/La.w};
    fx4 Rb = {1.f/Lb.x, 1.f/Lb.y, 1.f/Lb.z, 1.f/Lb.w};
    fx4 Rc = {1.f/Lc.x, 1.f/Lc.y, 1.f/Lc.z, 1.f/Lc.w};
    fx4 Rd = {1.f/Ld.x, 1.f/Ld.y, 1.f/Ld.z, 1.f/Ld.w};
    int bb = bh >> 2, h = bh & 3;
    uint16_t* op = O + (bb*KTOK + qt*128 + tq*32)*CC + h*DH + l31;
#pragma unroll
    for (int r = 0; r < 16; ++r){
      int qd = (r&3) + 8*(r>>2) + 4*hi;
      float rv = (r<4) ? Ra[r&3] : (r<8) ? Rb[r&3] : (r<12) ? Rc[r&3] : Rd[r&3];
      op[qd*CC] = f2bf(acc[r] * rv);
    }
  }
}

/* ---------------- K7: out-proj + residual + LayerNorm + scatter --------- */
__global__ __launch_bounds__(256) void k_outln(const uint16_t* __restrict__ O,
                                               const uint16_t* __restrict__ wob,
                                               const float* __restrict__ bo,
                                               const float* __restrict__ feats,
                                               const int* __restrict__ sel,
                                               const float* __restrict__ lnw,
                                               const float* __restrict__ lnb,
                                               float* __restrict__ out){
  __shared__ float red[16][4][2];
  int wave = threadIdx.x >> 6, lane = threadIdx.x & 63;
  int l15 = lane & 15, g = lane >> 4;
  int rt = blockIdx.x;
  int arow = rt*16 + l15;
  int jA = wave*32 + l15, jB = jA + 16;
  fx4 accA = {0,0,0,0}, accB = {0,0,0,0};
#pragma unroll
  for (int kk = 0; kk < 4; ++kk){
    sh8 aF = *(const sh8*)(O   + arow*CC + kk*32 + g*8);
    sh8 b0 = *(const sh8*)(wob + jA*CC   + kk*32 + g*8);
    sh8 b1 = *(const sh8*)(wob + jB*CC   + kk*32 + g*8);
    accA = mfma32(aF, b0, accA);
    accB = mfma32(aF, b1, accB);
  }
  float bjA = bo[jA], bjB = bo[jB];
  float hA[4], hB[4]; int gl[4];
#pragma unroll
  for (int i = 0; i < 4; ++i){
    int r = rt*16 + g*4 + i;
    int grow = sel[r];
    gl[i] = grow;
    hA[i] = accA[i] + bjA + feats[grow*CC + jA];
    hB[i] = accB[i] + bjB + feats[grow*CC + jB];
  }
#pragma unroll
  for (int i = 0; i < 4; ++i){
    float s  = hA[i] + hB[i];
    float s2 = hA[i]*hA[i] + hB[i]*hB[i];
    for (int mk = 1; mk < 16; mk <<= 1){ s += __shfl_xor(s, mk); s2 += __shfl_xor(s2, mk); }
    if (l15 == 0){ red[g*4+i][wave][0] = s; red[g*4+i][wave][1] = s2; }
  }
  __syncthreads();
  float w0 = lnw[jA], w1 = lnw[jB], b0v = lnb[jA], b1v = lnb[jB];
#pragma unroll
  for (int i = 0; i < 4; ++i){
    int rl = g*4 + i;
    float tot  = red[rl][0][0] + red[rl][1][0] + red[rl][2][0] + red[rl][3][0];
    float tot2 = red[rl][0][1] + red[rl][1][1] + red[rl][2][1] + red[rl][3][1];
    float mu  = tot  * (1.f/128.f);
    float var = tot2 * (1.f/128.f) - mu*mu;
    float rs = rsqrtf(var + 1e-5f);
    out[gl[i]*CC + jA] = (hA[i]-mu)*rs*w0 + b0v;
    out[gl[i]*CC + jB] = (hB[i]-mu)*rs*w1 + b1v;
  }
}

extern "C" void kernel_launch(void* const* d_in, const int* in_sizes, int n_in,
                              void* d_out, int out_size, void* d_ws, size_t ws_size,
                              hipStream_t stream){
  const float* feats = (const float*)d_in[0];
  /* d_in[1] = batch_idx (int64) — contiguous equal groups, unused */
  const float* wqkv  = (const float*)d_in[2];
  const float* bqkv  = (const float*)d_in[3];
  const float* wout  = (const float*)d_in[4];
  const float* bout  = (const float*)d_in[5];
  const float* lnw   = (const float*)d_in[6];
  const float* lnb   = (const float*)d_in[7];
  float* out = (float*)d_out;
  char* ws = (char*)d_ws;

  uint32_t* keys = (uint32_t*)(ws + 0);        /* 64KB  */
  int*      sel  = (int*)     (ws + 65536);    /* 32KB  */
  uint16_t* wqb  = (uint16_t*)(ws + 98304);    /* 96KB  */
  uint16_t* wob  = (uint16_t*)(ws + 196608);   /* 32KB  */
  uint16_t* Qg   = (uint16_t*)(ws + 2326528);  /* 2MB   */
  uint16_t* Kg   = (uint16_t*)(ws + 4423680);  /* 2MB   */
  uint16_t* Vt   = (uint16_t*)(ws + 6520832);  /* 2MB   */
  uint16_t* O    = (uint16_t*)(ws + 8617984);  /* 2MB   */

  hipLaunchKernelGGL(k_cpnw,   dim3(1280),   dim3(256),  0, stream,
                     feats, out, keys, wqkv, wout, wqb, wob);
  hipLaunchKernelGGL(k_select, dim3(2),      dim3(1024), 0, stream, keys, sel);
  hipLaunchKernelGGL(k_qkv,    dim3(512),    dim3(256),  0, stream,
                     feats, sel, wqb, bqkv, Qg, Kg, Vt);
  hipLaunchKernelGGL(k_attn,   dim3(32,8),   dim3(1024), 0, stream, Qg, Kg, Vt, O);
  hipLaunchKernelGGL(k_outln,  dim3(512),    dim3(256),  0, stream,
                     O, wob, bout, feats, sel, lnw, lnb, out);
}

// Round 22
// 70.216 us; speedup vs baseline: 1.0317x; 1.0129x over previous
//
#include <hip/hip_runtime.h>
#include <hip/hip_bf16.h>
#include <stdint.h>

#define NPB 8192
#define CB 2
#define CC 128
#define HH 4
#define KTOK 4096
#define DH 32
#define NTOK (CB*KTOK)
#define K2C 0.25503402f  /* log2(e)/sqrt(32) */

typedef __attribute__((ext_vector_type(8))) short sh8;
typedef __attribute__((ext_vector_type(4))) float fx4;
typedef __attribute__((ext_vector_type(16))) float fx16;
typedef __attribute__((ext_vector_type(2))) uint32_t ux2;
typedef __attribute__((ext_vector_type(4))) uint32_t ux4;

__device__ inline uint16_t f2bf(float f){
  uint32_t x = __float_as_uint(f);
  return (uint16_t)((x + 0x7FFFu + ((x>>16)&1u)) >> 16);
}
__device__ inline uint32_t pk2(float a, float b){
  return (uint32_t)f2bf(a) | ((uint32_t)f2bf(b) << 16);
}
__device__ inline float fast_exp2(float x){
#if __has_builtin(__builtin_amdgcn_exp2f)
  return __builtin_amdgcn_exp2f(x);
#else
  return exp2f(x);
#endif
}
__device__ inline uint32_t cvtpk1(float a, float b){
  uint32_t u;
  asm("v_cvt_pk_bf16_f32 %0, %1, %2" : "=v"(u) : "v"(a), "v"(b));
  return u;
}
__device__ inline fx4 mfma32(sh8 a, sh8 b, fx4 c){
  return __builtin_amdgcn_mfma_f32_16x16x32_bf16(a, b, c, 0, 0, 0);
}
__device__ inline fx16 mfma32x32(sh8 a, sh8 b, fx16 c){
  return __builtin_amdgcn_mfma_f32_32x32x16_bf16(a, b, c, 0, 0, 0);
}
__device__ inline void gload_lds(const uint16_t* g, uint16_t* l){
  __builtin_amdgcn_global_load_lds(
      (const __attribute__((address_space(1))) uint32_t*)g,
      (__attribute__((address_space(3))) uint32_t*)l,
      16, 0, 0);
}

/* -------- K1: per-row sqnorm keys only (no copy on critical path) ------- */
__global__ __launch_bounds__(256) void k_norms(const float* __restrict__ feats,
                                               uint32_t* __restrict__ keys){
  int row  = blockIdx.x*4 + (threadIdx.x>>6);
  int lane = threadIdx.x & 63;
  float2 v = *(const float2*)(feats + row*CC + lane*2);
  float s = v.x*v.x + v.y*v.y;
  for (int m = 1; m < 64; m <<= 1) s += __shfl_xor(s, m);
  if (lane == 0) keys[row] = __float_as_uint(s);  /* >=0 -> monotone as uint */
}

/* --- K2: top-4096 selection (blocks 0-1) + weight conversion (2-65) ----- */
__global__ __launch_bounds__(1024) void k_select(const uint32_t* __restrict__ keys,
                                                 int* __restrict__ sel,
                                                 const float* __restrict__ wq,
                                                 const float* __restrict__ wo,
                                                 uint16_t* __restrict__ wqb,
                                                 uint16_t* __restrict__ wob){
  int tid = threadIdx.x, batch = blockIdx.x;
  if (batch >= 2){
    int i = (batch - 2)*1024 + tid;   /* 0..65535 */
    if (i < 3*CC*CC) wqb[i] = f2bf(wq[i]);
    else { int j = i - 3*CC*CC; wob[j] = f2bf(wo[j]); }
    return;
  }
  __shared__ uint32_t ka[NPB];
  __shared__ uint32_t hist[16*257];
  __shared__ uint32_t sh_prefix, sh_r;
  __shared__ int wsum[17];
  int wv16 = tid >> 6;
  for (int i = tid; i < NPB; i += 1024) ka[i] = keys[batch*NPB + i];
  if (tid == 0){ sh_prefix = 0u; sh_r = KTOK; }
  __syncthreads();
  for (int pass = 0; pass < 4; ++pass){
    int shift = 24 - 8*pass;
    for (int i = tid; i < 16*257; i += 1024) hist[i] = 0u;
    __syncthreads();
    uint32_t pref = sh_prefix;
    uint32_t r0   = sh_r;
    uint32_t mask = (pass == 0) ? 0u : (0xFFFFFFFFu << (shift + 8));
    uint32_t* myh = &hist[wv16*257];
    for (int e = 0; e < 8; ++e){
      uint32_t k = ka[tid*8 + e];
      if ((k & mask) == pref) atomicAdd(&myh[(k >> shift) & 255], 1u);
    }
    __syncthreads();
    if (tid < 64){
      int lane = tid;
      uint32_t h0v = 0, h1v = 0, h2v = 0, h3v = 0;
      int b0 = lane*4;
#pragma unroll
      for (int w = 0; w < 16; ++w){
        const uint32_t* hw = &hist[w*257 + b0];
        h0v += hw[0]; h1v += hw[1]; h2v += hw[2]; h3v += hw[3];
      }
      uint32_t s3 = h3v, s2 = h2v + s3, s1 = h1v + s2, s0 = h0v + s1;
      uint32_t incl = s0;
      for (int d = 1; d < 64; d <<= 1){
        uint32_t t = __shfl_down(incl, d);
        if (lane + d < 64) incl += t;
      }
      uint32_t exA = incl - s0;
      uint32_t sfx[4] = {s0, s1, s2, s3};
      uint32_t hh[4]  = {h0v, h1v, h2v, h3v};
#pragma unroll
      for (int k = 0; k < 4; ++k){
        uint32_t inc_b = exA + sfx[k];
        uint32_t Sx    = inc_b - hh[k];
        if (Sx < r0 && inc_b >= r0){
          sh_prefix = pref | ((uint32_t)(b0 + k) << shift);
          sh_r = r0 - Sx;
        }
      }
    }
    __syncthreads();
  }
  uint32_t T = sh_prefix; int need = (int)sh_r;
  int lgt = 0, leq = 0;
  for (int e = 0; e < 8; ++e){
    uint32_t k = ka[tid*8 + e];
    lgt += (k > T); leq += (k == T);
  }
  int lane = tid & 63, wv = tid >> 6;
  int egt, tgt, eeq;
  {
    __syncthreads();
    int incl = lgt;
    for (int d = 1; d < 64; d <<= 1){ int t = __shfl_up(incl, d); if (lane >= d) incl += t; }
    if (lane == 63) wsum[wv] = incl;
    __syncthreads();
    if (tid == 0){ int run = 0; for (int w = 0; w < 16; ++w){ int t = wsum[w]; wsum[w] = run; run += t; } wsum[16] = run; }
    __syncthreads();
    egt = wsum[wv] + incl - lgt; tgt = wsum[16];
  }
  {
    __syncthreads();
    int incl = leq;
    for (int d = 1; d < 64; d <<= 1){ int t = __shfl_up(incl, d); if (lane >= d) incl += t; }
    if (lane == 63) wsum[wv] = incl;
    __syncthreads();
    if (tid == 0){ int run = 0; for (int w = 0; w < 16; ++w){ int t = wsum[w]; wsum[w] = run; run += t; } }
    __syncthreads();
    eeq = wsum[wv] + incl - leq;
  }
  int chi = tgt, gpos = egt, epos = eeq;
  for (int e = 0; e < 8; ++e){
    int i = tid*8 + e;
    uint32_t k = ka[i];
    if (k > T){ sel[batch*KTOK + (gpos++)] = batch*NPB + i; }
    else if (k == T){ if (epos < need) sel[batch*KTOK + chi + epos] = batch*NPB + i; epos++; }
  }
}

/* -- K5: QKV GEMM + fused gather (blocks 0-511)
      + whole-array feats->out copy (blocks 512-2559, overlapped) --------- */
__global__ __launch_bounds__(256) void k_qkv(const float* __restrict__ feats,
                                             const int* __restrict__ sel,
                                             const uint16_t* __restrict__ wqb,
                                             const float* __restrict__ bias,
                                             uint16_t* __restrict__ Qg,
                                             uint16_t* __restrict__ Kg,
                                             uint16_t* __restrict__ Vt,
                                             float* __restrict__ out){
  int bx = blockIdx.x;
  if (bx >= 512){
    /* copy blocks: 524288 float4 total; selected rows overwritten by outln */
    int i = (bx - 512)*256 + threadIdx.x;
    ((float4*)out)[i] = ((const float4*)feats)[i];
    return;
  }
  int wave = threadIdx.x >> 6, lane = threadIdx.x & 63;
  int l15 = lane & 15, g = lane >> 4;
  int rt = bx;                       /* 512 row tiles */
  int arow = rt*16 + l15;
  int grow = sel[arow];
  sh8 aF[4];
#pragma unroll
  for (int kk = 0; kk < 4; ++kk){
    const float* src = feats + grow*CC + kk*32 + g*8;
    float4 v0 = *(const float4*)(src);
    float4 v1 = *(const float4*)(src + 4);
    ux4 u;
    u.x = cvtpk1(v0.x, v0.y);
    u.y = cvtpk1(v0.z, v0.w);
    u.z = cvtpk1(v1.x, v1.y);
    u.w = cvtpk1(v1.z, v1.w);
    aF[kk] = *(sh8*)&u;
  }
  int tbase = rt*16;
  int b  = tbase >> 12;
  int q0 = (tbase & 4095) + g*4;     /* 4 consecutive within-batch slots */
#pragma unroll
  for (int cg = 0; cg < 6; ++cg){
    int bcol = (cg*4 + wave)*16 + l15;
    fx4 acc = {0.f,0.f,0.f,0.f};
#pragma unroll
    for (int kk = 0; kk < 4; ++kk){
      sh8 bF = *(const sh8*)(wqb + bcol*CC + kk*32 + g*8);
      acc = mfma32(aF[kk], bF, acc);
    }
    int j = bcol;
    float bj = bias[j];
    if (j < CC){
      int h = j >> 5, d = j & 31;
      uint16_t* p = Qg + ((b*HH + h)*KTOK + q0)*DH + d;
#pragma unroll
      for (int i = 0; i < 4; ++i) p[i*DH] = f2bf((acc[i] + bj) * K2C);
    } else if (j < 2*CC){
      int jj = j - CC; int h = jj >> 5, d = jj & 31;
      uint16_t* p = Kg + ((b*HH + h)*KTOK + q0)*DH + d;
#pragma unroll
      for (int i = 0; i < 4; ++i) p[i*DH] = f2bf(acc[i] + bj);
    } else {
      int jj = j - 2*CC; int h = jj >> 5, d = jj & 31;
      uint16_t* p = Vt + ((b*HH + h)*DH + d)*KTOK + q0;
      ux2 w; w.x = pk2(acc[0]+bj, acc[1]+bj); w.y = pk2(acc[2]+bj, acc[3]+bj);
      *(ux2*)p = w;
    }
  }
}

/* ---- K6: attention — R19/R21-proven (128q, K-perm kappa, MFMA l-sum) --- */
__global__ __launch_bounds__(1024) void k_attn(const uint16_t* __restrict__ Qg,
                                               const uint16_t* __restrict__ Kg,
                                               const uint16_t* __restrict__ Vtg,
                                               uint16_t* __restrict__ O){
  __shared__ __align__(16) char lds[68096];
  int tid = threadIdx.x;
  int wv = tid >> 6, lane = tid & 63;
  int l31 = lane & 31, hi = lane >> 5;
  int seg = wv & 3, tq = wv >> 2;      /* seg 0..3, tq 0..3 */
  int bh = blockIdx.y;
  int qt = blockIdx.x;                 /* 32 q128-tiles per bh */
  const uint16_t* Qp = Qg  + bh*KTOK*DH;
  const uint16_t* Kp = Kg  + bh*KTOK*DH;
  const uint16_t* Vp = Vtg + bh*DH*KTOK;
  int q = qt*128 + tq*32 + l31;
  sh8 qF0 = *(const sh8*)(Qp + q*DH + hi*8);        /* B: col=q, k=dh 0..15  */
  sh8 qF1 = *(const sh8*)(Qp + q*DH + 16 + hi*8);   /* B: col=q, k=dh 16..31 */

  uint16_t* st = (uint16_t*)lds;   /* [2 buf][4 seg][K0|K1|V0|V1] 1024-elem blocks */
  int r16 = lane >> 2;
  int kr  = (r16 & 3) | ((r16 & 4) << 1) | ((r16 & 8) >> 1);  /* kappa source row */
  int sx  = ((lane & 3) ^ ((r16 >> 1) & 3)) * 8;   /* dest-row-keyed swizzled slot */
  int sseg = wv & 3;
  int skey0 = sseg*1024;

  /* prologue: chunk 0 -> buf0 (waves 0-3: K permuted, 4-7: V natural) */
  if (wv < 4){
    const uint16_t* kg = Kp + skey0*DH;
    uint16_t* d = st + sseg*4096;
#pragma unroll
    for (int ks = 0; ks < 2; ++ks){
      gload_lds(kg + (ks*32 + kr)*DH + sx,      d + ks*1024 + 0);
      gload_lds(kg + (ks*32 + 16 + kr)*DH + sx, d + ks*1024 + 512);
    }
  } else if (wv < 8){
    const uint16_t* vg = Vp + skey0;
    uint16_t* d = st + sseg*4096 + 2048;
#pragma unroll
    for (int ks = 0; ks < 2; ++ks){
      gload_lds(vg + r16*KTOK + ks*32 + sx,        d + ks*1024 + 0);
      gload_lds(vg + (16+r16)*KTOK + ks*32 + sx,   d + ks*1024 + 512);
    }
  }
  asm volatile("s_waitcnt vmcnt(0)" ::: "memory");
  __syncthreads();

  fx16 acc  = {0,0,0,0,0,0,0,0,0,0,0,0,0,0,0,0};
  fx16 accl = {0,0,0,0,0,0,0,0,0,0,0,0,0,0,0,0};
  const fx16 z16 = {0,0,0,0,0,0,0,0,0,0,0,0,0,0,0,0};
  const short ONEB = (short)0x3F80;
  sh8 onesB = {ONEB,ONEB,ONEB,ONEB,ONEB,ONEB,ONEB,ONEB};
  int swz = (l31 >> 1) & 3;
  int koff0 = l31*32 + ((hi     ^ swz)*8);
  int koff1 = l31*32 + (((hi+2) ^ swz)*8);

  for (int t = 0; t < 16; ++t){
    int b = t & 1;
    if (t < 15){
      int nk = skey0 + (t+1)*64;
      if (wv < 4){
        const uint16_t* kg = Kp + nk*DH;
        uint16_t* d = st + ((b^1)*4 + sseg)*4096;
#pragma unroll
        for (int ks = 0; ks < 2; ++ks){
          gload_lds(kg + (ks*32 + kr)*DH + sx,      d + ks*1024 + 0);
          gload_lds(kg + (ks*32 + 16 + kr)*DH + sx, d + ks*1024 + 512);
        }
      } else if (wv < 8){
        const uint16_t* vg = Vp + nk;
        uint16_t* d = st + ((b^1)*4 + sseg)*4096 + 2048;
#pragma unroll
        for (int ks = 0; ks < 2; ++ks){
          gload_lds(vg + r16*KTOK + ks*32 + sx,        d + ks*1024 + 0);
          gload_lds(vg + (16+r16)*KTOK + ks*32 + sx,   d + ks*1024 + 512);
        }
      }
    }
    const uint16_t* base = st + (b*4 + seg)*4096;
#pragma unroll
    for (int ks = 0; ks < 2; ++ks){
      const uint16_t* bK = base + ks*1024;
      const uint16_t* bV = base + 2048 + ks*1024;
      sh8 kA0 = *(const sh8*)(bK + koff0);
      sh8 kA1 = *(const sh8*)(bK + koff1);
      fx16 S = mfma32x32(kA0, qF0, z16);
      S = mfma32x32(kA1, qF1, S);
      float e[16];
#pragma unroll
      for (int r = 0; r < 16; ++r) e[r] = fast_exp2(S[r]);
      ux4 w0, w1;
      w0.x = cvtpk1(e[0],  e[1]);  w0.y = cvtpk1(e[2],  e[3]);
      w0.z = cvtpk1(e[4],  e[5]);  w0.w = cvtpk1(e[6],  e[7]);
      w1.x = cvtpk1(e[8],  e[9]);  w1.y = cvtpk1(e[10], e[11]);
      w1.z = cvtpk1(e[12], e[13]); w1.w = cvtpk1(e[14], e[15]);
      sh8 pa0 = *(sh8*)&w0;   /* A: row=q, k=keys 0..15 (kappa-matched) */
      sh8 pa1 = *(sh8*)&w1;   /* A: row=q, k=keys 16..31                */
      sh8 vB0 = *(const sh8*)(bV + koff0);
      sh8 vB1 = *(const sh8*)(bV + koff1);
      acc  = mfma32x32(pa0, vB0, acc);
      acc  = mfma32x32(pa1, vB1, acc);
      accl = mfma32x32(pa0, onesB, accl);
      accl = mfma32x32(pa1, onesB, accl);
    }
    asm volatile("s_waitcnt vmcnt(0)" ::: "memory");
    __syncthreads();
  }

  /* combine 4 segments x 4 tiles; staging LDS reused after final barrier */
  float* cmb = (float*)lds;                    /* [4 tq][4 seg][64][16] = 64KB */
  float* lwp = (float*)(lds + 65536);          /* [16][32] = 2KB               */
  float* ltr = (float*)(lds + 65536 + 2048);   /* [4][32]                      */
#pragma unroll
  for (int i = 0; i < 16; i += 4){
    fx4 p = {acc[i], acc[i+1], acc[i+2], acc[i+3]};
    *(fx4*)&cmb[((tq*4 + seg)*64 + lane)*16 + i] = p;
  }
  if (l31 == 0){   /* lanes 0,32: accl[r] = l(q=crow(r,hi)), same every col */
#pragma unroll
    for (int r = 0; r < 16; ++r)
      lwp[wv*32 + (r&3) + 8*(r>>2) + 4*hi] = accl[r];
  }
  __syncthreads();
  if (seg == 0){   /* waves 0,4,8,12 -> tiles tq=0..3 */
#pragma unroll
    for (int s = 1; s < 4; ++s){
#pragma unroll
      for (int i = 0; i < 16; i += 4){
        fx4 p = *(const fx4*)&cmb[((tq*4 + s)*64 + lane)*16 + i];
        acc[i] += p.x; acc[i+1] += p.y; acc[i+2] += p.z; acc[i+3] += p.w;
      }
    }
    float lt = (lwp[(tq*4+0)*32 + l31] + lwp[(tq*4+1)*32 + l31])
             + (lwp[(tq*4+2)*32 + l31] + lwp[(tq*4+3)*32 + l31]);
    if (!hi) ltr[tq*32 + l31] = lt;
    fx4 La = *(const fx4*)&ltr[tq*32 + 4*hi];
    fx4 Lb = *(const fx4*)&ltr[tq*32 + 8 + 4*hi];
    fx4 Lc = *(const fx4*)&ltr[tq*32 + 16 + 4*hi];
    fx4 Ld = *(const fx4*)&ltr[tq*32 + 24 + 4*hi];
    fx4 Ra = {1.f/La.x, 1.f/La.y, 1.f/La.z, 1.f/La.w};
    fx4 Rb = {1.f/Lb.x, 1.f/Lb.y, 1.f/Lb.z, 1.f/Lb.w};
    fx4 Rc = {1.f/Lc.x, 1.f/Lc.y, 1.f/Lc.z, 1.f/Lc.w};
    fx4 Rd = {1.f/Ld.x, 1.f/Ld.y, 1.f/Ld.z, 1.f/Ld.w};
    int bb = bh >> 2, h = bh & 3;
    uint16_t* op = O + (bb*KTOK + qt*128 + tq*32)*CC + h*DH + l31;
#pragma unroll
    for (int r = 0; r < 16; ++r){
      int qd = (r&3) + 8*(r>>2) + 4*hi;
      float rv = (r<4) ? Ra[r&3] : (r<8) ? Rb[r&3] : (r<12) ? Rc[r&3] : Rd[r&3];
      op[qd*CC] = f2bf(acc[r] * rv);
    }
  }
}

/* ---------------- K7: out-proj + residual + LayerNorm + scatter --------- */
__global__ __launch_bounds__(256) void k_outln(const uint16_t* __restrict__ O,
                                               const uint16_t* __restrict__ wob,
                                               const float* __restrict__ bo,
                                               const float* __restrict__ feats,
                                               const int* __restrict__ sel,
                                               const float* __restrict__ lnw,
                                               const float* __restrict__ lnb,
                                               float* __restrict__ out){
  __shared__ float red[16][4][2];
  int wave = threadIdx.x >> 6, lane = threadIdx.x & 63;
  int l15 = lane & 15, g = lane >> 4;
  int rt = blockIdx.x;
  int arow = rt*16 + l15;
  int jA = wave*32 + l15, jB = jA + 16;
  fx4 accA = {0,0,0,0}, accB = {0,0,0,0};
#pragma unroll
  for (int kk = 0; kk < 4; ++kk){
    sh8 aF = *(const sh8*)(O   + arow*CC + kk*32 + g*8);
    sh8 b0 = *(const sh8*)(wob + jA*CC   + kk*32 + g*8);
    sh8 b1 = *(const sh8*)(wob + jB*CC   + kk*32 + g*8);
    accA = mfma32(aF, b0, accA);
    accB = mfma32(aF, b1, accB);
  }
  float bjA = bo[jA], bjB = bo[jB];
  float hA[4], hB[4]; int gl[4];
#pragma unroll
  for (int i = 0; i < 4; ++i){
    int r = rt*16 + g*4 + i;
    int grow = sel[r];
    gl[i] = grow;
    hA[i] = accA[i] + bjA + feats[grow*CC + jA];
    hB[i] = accB[i] + bjB + feats[grow*CC + jB];
  }
#pragma unroll
  for (int i = 0; i < 4; ++i){
    float s  = hA[i] + hB[i];
    float s2 = hA[i]*hA[i] + hB[i]*hB[i];
    for (int mk = 1; mk < 16; mk <<= 1){ s += __shfl_xor(s, mk); s2 += __shfl_xor(s2, mk); }
    if (l15 == 0){ red[g*4+i][wave][0] = s; red[g*4+i][wave][1] = s2; }
  }
  __syncthreads();
  float w0 = lnw[jA], w1 = lnw[jB], b0v = lnb[jA], b1v = lnb[jB];
#pragma unroll
  for (int i = 0; i < 4; ++i){
    int rl = g*4 + i;
    float tot  = red[rl][0][0] + red[rl][1][0] + red[rl][2][0] + red[rl][3][0];
    float tot2 = red[rl][0][1] + red[rl][1][1] + red[rl][2][1] + red[rl][3][1];
    float mu  = tot  * (1.f/128.f);
    float var = tot2 * (1.f/128.f) - mu*mu;
    float rs = rsqrtf(var + 1e-5f);
    out[gl[i]*CC + jA] = (hA[i]-mu)*rs*w0 + b0v;
    out[gl[i]*CC + jB] = (hB[i]-mu)*rs*w1 + b1v;
  }
}

extern "C" void kernel_launch(void* const* d_in, const int* in_sizes, int n_in,
                              void* d_out, int out_size, void* d_ws, size_t ws_size,
                              hipStream_t stream){
  const float* feats = (const float*)d_in[0];
  /* d_in[1] = batch_idx (int64) — contiguous equal groups, unused */
  const float* wqkv  = (const float*)d_in[2];
  const float* bqkv  = (const float*)d_in[3];
  const float* wout  = (const float*)d_in[4];
  const float* bout  = (const float*)d_in[5];
  const float* lnw   = (const float*)d_in[6];
  const float* lnb   = (const float*)d_in[7];
  float* out = (float*)d_out;
  char* ws = (char*)d_ws;

  uint32_t* keys = (uint32_t*)(ws + 0);        /* 64KB  */
  int*      sel  = (int*)     (ws + 65536);    /* 32KB  */
  uint16_t* wqb  = (uint16_t*)(ws + 98304);    /* 96KB  */
  uint16_t* wob  = (uint16_t*)(ws + 196608);   /* 32KB  */
  uint16_t* Qg   = (uint16_t*)(ws + 2326528);  /* 2MB   */
  uint16_t* Kg   = (uint16_t*)(ws + 4423680);  /* 2MB   */
  uint16_t* Vt   = (uint16_t*)(ws + 6520832);  /* 2MB   */
  uint16_t* O    = (uint16_t*)(ws + 8617984);  /* 2MB   */

  hipLaunchKernelGGL(k_norms,  dim3(4096),   dim3(256),  0, stream, feats, keys);
  hipLaunchKernelGGL(k_select, dim3(66),     dim3(1024), 0, stream,
                     keys, sel, wqkv, wout, wqb, wob);
  hipLaunchKernelGGL(k_qkv,    dim3(2560),   dim3(256),  0, stream,
                     feats, sel, wqb, bqkv, Qg, Kg, Vt, out);
  hipLaunchKernelGGL(k_attn,   dim3(32,8),   dim3(1024), 0, stream, Qg, Kg, Vt, O);
  hipLaunchKernelGGL(k_outln,  dim3(512),    dim3(256),  0, stream,
                     O, wob, bout, feats, sel, lnw, lnb, out);
}